// Round 16
// baseline (202.015 us; speedup 1.0000x reference)
//
#include <hip/hip_runtime.h>

#define S_LEN 4096
#define HIDDEN 1024
#define NH 8
#define NKV 2
#define HD 128
#define WIN 2048

typedef short bf16x8 __attribute__((ext_vector_type(8)));
typedef short bf16x4 __attribute__((ext_vector_type(4)));
typedef float f32x4 __attribute__((ext_vector_type(4)));
typedef unsigned short u16x4 __attribute__((ext_vector_type(4)));

__device__ __forceinline__ unsigned short f2b(float f) {
    unsigned int u = __builtin_bit_cast(unsigned int, f);
    u += 0x7fffu + ((u >> 16) & 1u);     // round-to-nearest-even
    return (unsigned short)(u >> 16);
}
__device__ __forceinline__ float b2f(unsigned short u) {
    unsigned int x = ((unsigned int)u) << 16;
    return __builtin_bit_cast(float, x);
}

// async global->LDS, 16B per lane, lands at ldsbase + lane*16 (wave-uniform base)
__device__ __forceinline__ void gl_lds16(const unsigned short* g, unsigned short* l) {
    __builtin_amdgcn_global_load_lds(
        (const __attribute__((address_space(1))) unsigned int*)g,
        (__attribute__((address_space(3))) unsigned int*)l, 16, 0, 0);
}

// s_waitcnt immediates (gfx9): vmcnt[3:0]|[15:14], exp[6:4], lgkm[11:8]
#define WAIT_VM4   0x0F74   // vmcnt<=4
#define WAIT_VM0   0x0F70   // vmcnt==0
#define WAIT_LGKM0 0xC07F   // lgkmcnt==0
#define MEMFENCE() __asm__ volatile("" ::: "memory")

// ---------------------------------------------------------------------------
// One-shot fp32 -> bf16 of the five input tensors (float4 granularity).
// ---------------------------------------------------------------------------
__global__ __launch_bounds__(256) void cvt5(
    const float* __restrict__ s0, unsigned short* __restrict__ t0, int n0,
    const float* __restrict__ s1, unsigned short* __restrict__ t1, int n1,
    const float* __restrict__ s2, unsigned short* __restrict__ t2, int n2,
    const float* __restrict__ s3, unsigned short* __restrict__ t3, int n3,
    const float* __restrict__ s4, unsigned short* __restrict__ t4, int n4)
{
    int i = blockIdx.x * 256 + threadIdx.x;   // float4 index
    const float* s; unsigned short* t;
    if (i < n0)              { s = s0; t = t0; }
    else if ((i -= n0) < n1) { s = s1; t = t1; }
    else if ((i -= n1) < n2) { s = s2; t = t2; }
    else if ((i -= n2) < n3) { s = s3; t = t3; }
    else if ((i -= n3) < n4) { s = s4; t = t4; }
    else return;
    f32x4 v = *(const f32x4*)(s + (size_t)i * 4);
    u16x4 r = { f2b(v[0]), f2b(v[1]), f2b(v[2]), f2b(v[3]) };
    *(u16x4*)(t + (size_t)i * 4) = r;
}

// ---------------------------------------------------------------------------
// Pipelined m97 GEMM (output projection): tile 128x128, BK=32, LDS
// TRIPLE-buffered, single barrier per K-step (R13/R15, frozen).
// ---------------------------------------------------------------------------
__global__ __launch_bounds__(256, 2) void gemm128(
    const unsigned short* __restrict__ A, const unsigned short* __restrict__ W,
    float* __restrict__ Cf, unsigned short* __restrict__ Cb,
    int M, int N, int K)
{
    __shared__ alignas(16) unsigned short As[3][128 * 32];   // 24 KB
    __shared__ alignas(16) unsigned short Bs[3][128 * 32];   // 24 KB

    int lane = threadIdx.x & 63;
    int w = threadIdx.x >> 6;
    int l15 = lane & 15, quad = lane >> 4;

    int tiles_n = N >> 7;
    int mt0 = (int)blockIdx.x / tiles_n;
    int nt0 = (int)blockIdx.x - mt0 * tiles_n;

    size_t goffA[2], goffB[2];
    #pragma unroll
    for (int is = 0; is < 2; ++is) {
        int s = w * 128 + is * 64 + lane;
        int row = s >> 2, spos = s & 3;
        int kblk = spos ^ ((row >> 1) & 3);
        goffA[is] = (size_t)(mt0 * 128 + row) * K + kblk * 8;
        goffB[is] = (size_t)(nt0 * 128 + row) * K + kblk * 8;
    }

    int arow0 = (w >> 1) * 64;
    int brow0 = (w & 1) * 64;
    int aoff[4], boff[4];
    #pragma unroll
    for (int t = 0; t < 4; ++t) {
        int ra = arow0 + t * 16 + l15;
        aoff[t] = (ra * 4 + (quad ^ ((ra >> 1) & 3))) * 8;
        int rb = brow0 + t * 16 + l15;
        boff[t] = (rb * 4 + (quad ^ ((rb >> 1) & 3))) * 8;
    }

    f32x4 acc[4][4];
    #pragma unroll
    for (int i = 0; i < 4; ++i)
        #pragma unroll
        for (int j = 0; j < 4; ++j) acc[i][j] = (f32x4){0.f, 0.f, 0.f, 0.f};

    auto stage = [&](int i) {
        int b = i % 3, k0 = i * 32;
        gl_lds16(A + goffA[0] + k0, &As[b][(w * 128 + 0) * 8]);
        gl_lds16(A + goffA[1] + k0, &As[b][(w * 128 + 64) * 8]);
        gl_lds16(W + goffB[0] + k0, &Bs[b][(w * 128 + 0) * 8]);
        gl_lds16(W + goffB[1] + k0, &Bs[b][(w * 128 + 64) * 8]);
    };

    int nk = K >> 5;
    stage(0);
    if (nk > 1) stage(1);
    for (int i = 0; i < nk; ++i) {
        MEMFENCE();
        if (i + 1 < nk) __builtin_amdgcn_s_waitcnt(WAIT_VM4);
        else            __builtin_amdgcn_s_waitcnt(WAIT_VM0);
        __builtin_amdgcn_s_barrier();
        MEMFENCE();
        if (i + 2 < nk) stage(i + 2);

        const unsigned short* Ab = &As[i % 3][0];
        const unsigned short* Bb = &Bs[i % 3][0];
        bf16x8 af[4], bf_[4];
        #pragma unroll
        for (int t = 0; t < 4; ++t) {
            af[t]  = *(const bf16x8*)(Ab + aoff[t]);
            bf_[t] = *(const bf16x8*)(Bb + boff[t]);
        }
        #pragma unroll
        for (int i2 = 0; i2 < 4; ++i2)
            #pragma unroll
            for (int j = 0; j < 4; ++j)
                acc[i2][j] = __builtin_amdgcn_mfma_f32_16x16x32_bf16(af[i2], bf_[j], acc[i2][j], 0, 0, 0);
        MEMFENCE();
    }

    #pragma unroll
    for (int i = 0; i < 4; ++i) {
        int row0 = mt0 * 128 + arow0 + i * 16 + quad * 4;
        #pragma unroll
        for (int j = 0; j < 4; ++j) {
            int col = nt0 * 128 + brow0 + j * 16 + l15;
            if (Cf) {
                #pragma unroll
                for (int reg = 0; reg < 4; ++reg)
                    Cf[(size_t)(row0 + reg) * N + col] = acc[i][j][reg];
            } else {
                #pragma unroll
                for (int reg = 0; reg < 4; ++reg)
                    Cb[(size_t)(row0 + reg) * N + col] = f2b(acc[i][j][reg]);
            }
        }
    }
}

// ---------------------------------------------------------------------------
// QKV projection: triple-buffered K-loop + FUSED epilogues, staging pool
// aliased with rope/transpose LDS (R15, frozen).
// ---------------------------------------------------------------------------
#define QKVW (HIDDEN + 2 * NKV * HD)   // 1536
__global__ __launch_bounds__(256, 2) void gemmqkv(
    const unsigned short* __restrict__ A, const unsigned short* __restrict__ W,
    const int* __restrict__ pos,
    unsigned short* __restrict__ Qb, unsigned short* __restrict__ Kb,
    unsigned short* __restrict__ Vt)
{
    __shared__ alignas(16) char pool[49152];   // 48 KB
    unsigned short (*As)[128 * 32] = (unsigned short (*)[128 * 32])(pool);
    unsigned short (*Bs)[128 * 32] = (unsigned short (*)[128 * 32])(pool + 24576);
    float (*Ex)[32][68] = (float (*)[32][68])(pool);
    unsigned short* T = (unsigned short*)(pool);

    int lane = threadIdx.x & 63;
    int w = threadIdx.x >> 6;
    int l15 = lane & 15, quad = lane >> 4;

    const int K = HIDDEN;
    int mt0 = (int)blockIdx.x / 12;
    int nt0 = (int)blockIdx.x - mt0 * 12;

    size_t goffA[2], goffB[2];
    #pragma unroll
    for (int is = 0; is < 2; ++is) {
        int s = w * 128 + is * 64 + lane;
        int row = s >> 2, spos = s & 3;
        int kblk = spos ^ ((row >> 1) & 3);
        goffA[is] = (size_t)(mt0 * 128 + row) * K + kblk * 8;
        goffB[is] = (size_t)(nt0 * 128 + row) * K + kblk * 8;
    }

    int arow0 = (w >> 1) * 64;
    int brow0 = (w & 1) * 64;
    int aoff[4], boff[4];
    #pragma unroll
    for (int t = 0; t < 4; ++t) {
        int ra = arow0 + t * 16 + l15;
        aoff[t] = (ra * 4 + (quad ^ ((ra >> 1) & 3))) * 8;
        int rb = brow0 + t * 16 + l15;
        boff[t] = (rb * 4 + (quad ^ ((rb >> 1) & 3))) * 8;
    }

    f32x4 acc[4][4];
    #pragma unroll
    for (int i = 0; i < 4; ++i)
        #pragma unroll
        for (int j = 0; j < 4; ++j) acc[i][j] = (f32x4){0.f, 0.f, 0.f, 0.f};

    auto stage = [&](int i) {
        int b = i % 3, k0 = i * 32;
        gl_lds16(A + goffA[0] + k0, &As[b][(w * 128 + 0) * 8]);
        gl_lds16(A + goffA[1] + k0, &As[b][(w * 128 + 64) * 8]);
        gl_lds16(W + goffB[0] + k0, &Bs[b][(w * 128 + 0) * 8]);
        gl_lds16(W + goffB[1] + k0, &Bs[b][(w * 128 + 64) * 8]);
    };

    stage(0);
    stage(1);
    for (int i = 0; i < 32; ++i) {
        MEMFENCE();
        if (i + 1 < 32) __builtin_amdgcn_s_waitcnt(WAIT_VM4);
        else            __builtin_amdgcn_s_waitcnt(WAIT_VM0);
        __builtin_amdgcn_s_barrier();
        MEMFENCE();
        if (i + 2 < 32) stage(i + 2);

        const unsigned short* Ab = &As[i % 3][0];
        const unsigned short* Bb = &Bs[i % 3][0];
        bf16x8 af[4], bf_[4];
        #pragma unroll
        for (int t = 0; t < 4; ++t) {
            af[t]  = *(const bf16x8*)(Ab + aoff[t]);
            bf_[t] = *(const bf16x8*)(Bb + boff[t]);
        }
        #pragma unroll
        for (int i2 = 0; i2 < 4; ++i2)
            #pragma unroll
            for (int j = 0; j < 4; ++j)
                acc[i2][j] = __builtin_amdgcn_mfma_f32_16x16x32_bf16(af[i2], bf_[j], acc[i2][j], 0, 0, 0);
        MEMFENCE();
    }

    if (nt0 >= 10) {
        // ---- V: bf16 -> LDS tile [128 s][130 d-stride] -> transposed Vt
        int kv = nt0 - 10;
        __syncthreads();
        #pragma unroll
        for (int i = 0; i < 4; ++i) {
            int srow = arow0 + i * 16 + quad * 4;
            #pragma unroll
            for (int j = 0; j < 4; ++j) {
                int d = brow0 + j * 16 + l15;
                #pragma unroll
                for (int reg = 0; reg < 4; ++reg)
                    T[(srow + reg) * 130 + d] = f2b(acc[i][j][reg]);
            }
        }
        __syncthreads();
        int tid = threadIdx.x;
        int dl = tid >> 5;
        int sc4 = (tid & 31) * 4;
        #pragma unroll
        for (int it = 0; it < 16; ++it) {
            int d = it * 8 + dl;
            u16x4 v4 = { T[(sc4 + 0) * 130 + d], T[(sc4 + 1) * 130 + d],
                         T[(sc4 + 2) * 130 + d], T[(sc4 + 3) * 130 + d] };
            *(u16x4*)(Vt + (size_t)kv * HD * S_LEN + (size_t)d * S_LEN
                      + mt0 * 128 + sc4) = v4;
        }
        return;
    }

    // ---- Q/K: rope epilogue
    bool isQ = (nt0 < 8);
    int kv = nt0 - 8;
    bool is64 = (pos[1] == 0) && (pos[3] == 0);
    const float qscale = 0.08838834764831843f;

    float invf[4];
    #pragma unroll
    for (int j = 0; j < 4; ++j) {
        int d6 = (brow0 + j * 16 + l15) & 63;
        invf[j] = exp2f(-(float)d6 * (13.287712379549449f / 64.0f));
    }

    #pragma unroll
    for (int r2 = 0; r2 < 2; ++r2) {
        __syncthreads();
        #pragma unroll
        for (int ii = 0; ii < 2; ++ii) {
            int i = r2 * 2 + ii;
            #pragma unroll
            for (int j = 0; j < 4; ++j)
                #pragma unroll
                for (int reg = 0; reg < 4; ++reg)
                    Ex[w][ii * 16 + quad * 4 + reg][j * 16 + l15] = acc[i][j][reg];
        }
        __syncthreads();
        #pragma unroll
        for (int ii = 0; ii < 2; ++ii) {
            int i = r2 * 2 + ii;
            #pragma unroll
            for (int reg = 0; reg < 4; ++reg) {
                int s = mt0 * 128 + arow0 + i * 16 + quad * 4 + reg;
                int pv_ = is64 ? pos[2 * s] : pos[s];
                float pf = (float)pv_;
                #pragma unroll
                for (int j = 0; j < 4; ++j) {
                    float sn, cs;
                    __sincosf(pf * invf[j], &sn, &cs);
                    float a  = acc[i][j][reg];
                    float pr = Ex[w ^ 1][ii * 16 + quad * 4 + reg][j * 16 + l15];
                    int d_local = brow0 + j * 16 + l15;
                    float outv = (d_local < 64) ? (a * cs - pr * sn) : (a * cs + pr * sn);
                    if (isQ) {
                        Qb[(size_t)s * HIDDEN + nt0 * HD + d_local] = f2b(outv * qscale);
                    } else {
                        Kb[(size_t)kv * S_LEN * HD + (size_t)s * HD + d_local] = f2b(outv);
                    }
                }
            }
        }
    }
}

// ---------------------------------------------------------------------------
// Flash attention, 32 QUERIES PER WAVE (128 q/block, grid 256 = 1 block/CU):
// every K/V fragment LDS read now feeds TWO q-groups' MFMAs -> LDS bytes per
// output halve (attn was measured LDS-BW-bound: 128 KB reads/chunk-block ≈
// 1060 clk ≈ the 1180 cy/chunk observed).  Register-direct P (S^T operand
// swap), single barrier/chunk, issue-after-barrier prefetch (R12/R13).
// Window base fixed to cover the FIRST query's full window.
// ---------------------------------------------------------------------------
__global__ __launch_bounds__(256) void attn_coop(
    const unsigned short* __restrict__ Qb, const unsigned short* __restrict__ Kb,
    const unsigned short* __restrict__ Vt, unsigned short* __restrict__ Ctx)
{
    __shared__ alignas(16) unsigned short Klds[2][64 * 128];   // 32 KB
    __shared__ alignas(16) unsigned short Vlds[2][128 * 64];   // 32 KB

    int lane = threadIdx.x & 63;
    int w = threadIdx.x >> 6;
    int l15 = lane & 15, quad = lane >> 4;
    int h = blockIdx.y;
    int kv = h >> 2;                 // GROUPS = 4
    int qb = blockIdx.x * 128;
    int q16g[2] = { qb + w * 32, qb + w * 32 + 16 };

    // Q fragments for both 16-query groups (lane = query l15, regs = 8 d)
    bf16x8 a_q[2][4];
    #pragma unroll
    for (int g = 0; g < 2; ++g) {
        const unsigned short* qrow =
            Qb + (size_t)(q16g[g] + l15) * HIDDEN + h * HD + quad * 8;
        #pragma unroll
        for (int st = 0; st < 4; ++st) a_q[g][st] = *(const bf16x8*)(qrow + st * 32);
    }

    bf16x4 ones4;
    #pragma unroll
    for (int i = 0; i < 4; ++i) ones4[i] = (short)0x3F80;   // bf16 1.0

    // full window of the FIRST query, chunk-aligned down
    int lo = qb - (WIN - 1); if (lo < 0) lo = 0; lo &= ~63;
    int nch = (qb + 128 - lo) >> 6;   // <= 34

    // staging roles: waves 0,1 stage K; waves 2,3 stage V (8 issues each)
    const unsigned short* gbase;
    unsigned short* ldsdst[2];
    int myoff[8];
    int jmul;
    if (w < 2) {
        gbase = Kb + (size_t)kv * S_LEN * HD;
        ldsdst[0] = &Klds[0][w * 8 * 512];
        ldsdst[1] = &Klds[1][w * 8 * 512];
        jmul = HD;
        #pragma unroll
        for (int tt = 0; tt < 8; ++tt) {
            int t = w * 8 + tt;
            int key  = t * 4 + (lane >> 4);
            int dblk = (lane & 15) ^ (key & 15);
            myoff[tt] = key * HD + dblk * 8;
        }
    } else {
        gbase = Vt + (size_t)kv * HD * S_LEN;
        ldsdst[0] = &Vlds[0][(w - 2) * 8 * 512];
        ldsdst[1] = &Vlds[1][(w - 2) * 8 * 512];
        jmul = 1;
        #pragma unroll
        for (int tt = 0; tt < 8; ++tt) {
            int t = (w - 2) * 8 + tt;
            int d    = t * 8 + (lane >> 3);
            int kblk = (lane & 7) ^ (d & 7);
            myoff[tt] = d * S_LEN + kblk * 8;
        }
    }

    auto issue = [&](int c) {
        int j0 = lo + c * 64;
        const unsigned short* src = gbase + (size_t)j0 * jmul;
        unsigned short* dst = ldsdst[c & 1];
        #pragma unroll
        for (int tt = 0; tt < 8; ++tt)
            gl_lds16(src + myoff[tt], dst + tt * 512);
    };

    f32x4 o[2][9];                   // per group: 8 d-tiles + l row-sums
    #pragma unroll
    for (int g = 0; g < 2; ++g)
        #pragma unroll
        for (int nd = 0; nd < 9; ++nd) o[g][nd] = (f32x4){0.f, 0.f, 0.f, 0.f};

    issue(0);

    for (int c = 0; c < nch; ++c) {
        int j0 = lo + c * 64;

        MEMFENCE();
        __builtin_amdgcn_s_waitcnt(WAIT_VM0);   // my slice of chunk c landed
        __builtin_amdgcn_s_barrier();           // chunk staged; buf[c-1] drained
        MEMFENCE();
        if (c + 1 < nch) issue(c + 1);

        const unsigned short* Kc = &Klds[c & 1][0];
        const unsigned short* Vc = &Vlds[c & 1][0];

        // ---- S^T tiles for BOTH groups: each K-frag load feeds 2 MFMAs
        f32x4 sc[2][4];
        #pragma unroll
        for (int t = 0; t < 4; ++t) {
            sc[0][t] = (f32x4){0.f, 0.f, 0.f, 0.f};
            sc[1][t] = (f32x4){0.f, 0.f, 0.f, 0.f};
            int key = t * 16 + l15;
            #pragma unroll
            for (int st = 0; st < 4; ++st) {
                int off16 = key * 16 + ((st * 4 + quad) ^ (key & 15));
                bf16x8 ak = *(const bf16x8*)(Kc + off16 * 8);
                sc[0][t] = __builtin_amdgcn_mfma_f32_16x16x32_bf16(ak, a_q[0][st], sc[0][t], 0, 0, 0);
                sc[1][t] = __builtin_amdgcn_mfma_f32_16x16x32_bf16(ak, a_q[1][st], sc[1][t], 0, 0, 0);
            }
        }

        // ---- P^T = exp(S^T) per group; pack into K=16 A-fragments
        bf16x4 a_p[2][4];
        #pragma unroll
        for (int g = 0; g < 2; ++g) {
            int q16 = q16g[g];
            if (j0 + 63 <= q16 && j0 > q16 + 15 - WIN) {
                #pragma unroll
                for (int t = 0; t < 4; ++t)
                    #pragma unroll
                    for (int reg = 0; reg < 4; ++reg)
                        a_p[g][t][reg] = (short)f2b(__expf(sc[g][t][reg]));
            } else {
                int iq = q16 + l15;
                #pragma unroll
                for (int t = 0; t < 4; ++t) {
                    #pragma unroll
                    for (int reg = 0; reg < 4; ++reg) {
                        int key = j0 + t * 16 + quad * 4 + reg;
                        float pv = (key <= iq && key > iq - WIN) ? __expf(sc[g][t][reg]) : 0.f;
                        a_p[g][t][reg] = (short)f2b(pv);
                    }
                }
            }
        }

        // ---- O += P@V, l += P@1 : each V-frag load feeds 2 MFMAs
        #pragma unroll
        for (int t = 0; t < 4; ++t) {
            #pragma unroll
            for (int nd = 0; nd < 8; ++nd) {
                int d = nd * 16 + l15;
                int kblk = t * 2 + (quad >> 1);
                int slot = d * 8 + (kblk ^ (d & 7));
                bf16x4 bv = *(const bf16x4*)(Vc + slot * 8 + (quad & 1) * 4);
                o[0][nd] = __builtin_amdgcn_mfma_f32_16x16x16bf16_1k(a_p[0][t], bv, o[0][nd], 0, 0, 0);
                o[1][nd] = __builtin_amdgcn_mfma_f32_16x16x16bf16_1k(a_p[1][t], bv, o[1][nd], 0, 0, 0);
            }
            o[0][8] = __builtin_amdgcn_mfma_f32_16x16x16bf16_1k(a_p[0][t], ones4, o[0][8], 0, 0, 0);
            o[1][8] = __builtin_amdgcn_mfma_f32_16x16x16bf16_1k(a_p[1][t], ones4, o[1][8], 0, 0, 0);
        }
        MEMFENCE();
    }

    // ---- epilogue: ctx = O / l (C-layout: col=l15=d, row=quad*4+reg=q)
    #pragma unroll
    for (int g = 0; g < 2; ++g)
        #pragma unroll
        for (int nd = 0; nd < 8; ++nd) {
            int d = nd * 16 + l15;
            #pragma unroll
            for (int reg = 0; reg < 4; ++reg) {
                int q = q16g[g] + quad * 4 + reg;
                Ctx[(size_t)q * HIDDEN + h * HD + d] = f2b(o[g][nd][reg] / o[g][8][reg]);
            }
        }
}

// ---------------------------------------------------------------------------
extern "C" void kernel_launch(void* const* d_in, const int* in_sizes, int n_in,
                              void* d_out, int out_size, void* d_ws, size_t ws_size,
                              hipStream_t stream)
{
    const float* hidden = (const float*)d_in[0];
    const float* wq = (const float*)d_in[1];
    const float* wk = (const float*)d_in[2];
    const float* wv = (const float*)d_in[3];
    const float* wo = (const float*)d_in[4];
    const int* pos = (const int*)d_in[5];
    float* out = (float*)d_out;

    char* ws = (char*)d_ws;
    size_t off = 0;
    unsigned short* Hb   = (unsigned short*)(ws + off); off += (size_t)S_LEN * HIDDEN * 2;
    unsigned short* Wqkv = (unsigned short*)(ws + off); off += (size_t)QKVW * HIDDEN * 2;
    unsigned short* Wob  = (unsigned short*)(ws + off); off += (size_t)HIDDEN * HIDDEN * 2;
    unsigned short* Qb   = (unsigned short*)(ws + off); off += (size_t)S_LEN * HIDDEN * 2;
    unsigned short* Kb   = (unsigned short*)(ws + off); off += (size_t)S_LEN * NKV * HD * 2;
    unsigned short* Vt   = (unsigned short*)(ws + off); off += (size_t)S_LEN * NKV * HD * 2;
    unsigned short* Cb   = (unsigned short*)(ws + off); off += (size_t)S_LEN * HIDDEN * 2;

    const int n_h  = S_LEN * HIDDEN / 4;
    const int n_wq = HIDDEN * HIDDEN / 4;
    const int n_wk = NKV * HD * HIDDEN / 4;
    int tot4 = n_h + n_wq + 2 * n_wk + n_wq;
    cvt5<<<(tot4 + 255) / 256, 256, 0, stream>>>(
        hidden, Hb, n_h,
        wq, Wqkv, n_wq,
        wk, Wqkv + (size_t)HIDDEN * HIDDEN, n_wk,
        wv, Wqkv + (size_t)(HIDDEN + NKV * HD) * HIDDEN, n_wk,
        wo, Wob, n_wq);

    // fused QKV projection + RoPE + V-transpose epilogues (384 blocks)
    gemmqkv<<<(S_LEN / 128) * 12, 256, 0, stream>>>(
        Hb, Wqkv, pos, Qb, Kb, Vt);

    // flash attention: 128 q/block, 256 blocks = 1/CU
    attn_coop<<<dim3(S_LEN / 128, NH), 256, 0, stream>>>(Qb, Kb, Vt, Cb);

    // output projection -> fp32 d_out (256 blocks)
    gemm128<<<(S_LEN / 128) * (HIDDEN / 128), 256, 0, stream>>>(
        Cb, Wob, out, nullptr, S_LEN, HIDDEN, HIDDEN);
}

// Round 17
// 187.212 us; speedup vs baseline: 1.0791x; 1.0791x over previous
//
#include <hip/hip_runtime.h>

#define S_LEN 4096
#define HIDDEN 1024
#define NH 8
#define NKV 2
#define HD 128
#define WIN 2048

typedef short bf16x8 __attribute__((ext_vector_type(8)));
typedef short bf16x4 __attribute__((ext_vector_type(4)));
typedef float f32x4 __attribute__((ext_vector_type(4)));
typedef unsigned short u16x4 __attribute__((ext_vector_type(4)));

__device__ __forceinline__ unsigned short f2b(float f) {
    unsigned int u = __builtin_bit_cast(unsigned int, f);
    u += 0x7fffu + ((u >> 16) & 1u);     // round-to-nearest-even
    return (unsigned short)(u >> 16);
}
__device__ __forceinline__ float b2f(unsigned short u) {
    unsigned int x = ((unsigned int)u) << 16;
    return __builtin_bit_cast(float, x);
}

// async global->LDS, 16B per lane, lands at ldsbase + lane*16 (wave-uniform base)
__device__ __forceinline__ void gl_lds16(const unsigned short* g, unsigned short* l) {
    __builtin_amdgcn_global_load_lds(
        (const __attribute__((address_space(1))) unsigned int*)g,
        (__attribute__((address_space(3))) unsigned int*)l, 16, 0, 0);
}

// s_waitcnt immediates (gfx9): vmcnt[3:0]|[15:14], exp[6:4], lgkm[11:8]
#define WAIT_VM3   0x0F73   // vmcnt<=3
#define WAIT_VM0   0x0F70   // vmcnt==0
#define MEMFENCE() __asm__ volatile("" ::: "memory")

// ---------------------------------------------------------------------------
// One-shot fp32 -> bf16 of the five input tensors (float4 granularity).
// ---------------------------------------------------------------------------
__global__ __launch_bounds__(256) void cvt5(
    const float* __restrict__ s0, unsigned short* __restrict__ t0, int n0,
    const float* __restrict__ s1, unsigned short* __restrict__ t1, int n1,
    const float* __restrict__ s2, unsigned short* __restrict__ t2, int n2,
    const float* __restrict__ s3, unsigned short* __restrict__ t3, int n3,
    const float* __restrict__ s4, unsigned short* __restrict__ t4, int n4)
{
    int i = blockIdx.x * 256 + threadIdx.x;   // float4 index
    const float* s; unsigned short* t;
    if (i < n0)              { s = s0; t = t0; }
    else if ((i -= n0) < n1) { s = s1; t = t1; }
    else if ((i -= n1) < n2) { s = s2; t = t2; }
    else if ((i -= n2) < n3) { s = s3; t = t3; }
    else if ((i -= n3) < n4) { s = s4; t = t4; }
    else return;
    f32x4 v = *(const f32x4*)(s + (size_t)i * 4);
    u16x4 r = { f2b(v[0]), f2b(v[1]), f2b(v[2]), f2b(v[3]) };
    *(u16x4*)(t + (size_t)i * 4) = r;
}

// ---------------------------------------------------------------------------
// Output projection GEMM, tile 64x128 (R17: halved M-tile doubles the grid
// to 512 = 2 blocks/CU = 2 waves/SIMD; the 128x128 version ran 1 wave/SIMD,
// fully latency-exposed).  Triple-buffered, 3 staging issues/wave/K-step
// (1 A + 2 B), single barrier per K-step, vmcnt(3) guard.
// Wave tile 32x64: acc[2][4], 8 MFMA + 6 ds_read_b128 per iter.
// ---------------------------------------------------------------------------
__global__ __launch_bounds__(256, 2) void gemm128(
    const unsigned short* __restrict__ A, const unsigned short* __restrict__ W,
    float* __restrict__ Cf, unsigned short* __restrict__ Cb,
    int M, int N, int K)
{
    __shared__ alignas(16) unsigned short As[3][64 * 32];    // 12 KB
    __shared__ alignas(16) unsigned short Bs[3][128 * 32];   // 24 KB

    int lane = threadIdx.x & 63;
    int w = threadIdx.x >> 6;
    int l15 = lane & 15, quad = lane >> 4;

    int tiles_n = N >> 7;
    int mt0 = (int)blockIdx.x / tiles_n;
    int nt0 = (int)blockIdx.x - mt0 * tiles_n;

    // staging: A 64x4=256 slots (1 issue/wave), B 128x4=512 slots (2/wave)
    size_t goffA;
    {
        int s = w * 64 + lane;
        int row = s >> 2, spos = s & 3;
        int kblk = spos ^ ((row >> 1) & 3);
        goffA = (size_t)(mt0 * 64 + row) * K + kblk * 8;
    }
    size_t goffB[2];
    #pragma unroll
    for (int is = 0; is < 2; ++is) {
        int s = w * 128 + is * 64 + lane;
        int row = s >> 2, spos = s & 3;
        int kblk = spos ^ ((row >> 1) & 3);
        goffB[is] = (size_t)(nt0 * 128 + row) * K + kblk * 8;
    }

    int arow0 = (w >> 1) * 32;
    int brow0 = (w & 1) * 64;
    int aoff[2], boff[4];
    #pragma unroll
    for (int t = 0; t < 2; ++t) {
        int ra = arow0 + t * 16 + l15;
        aoff[t] = (ra * 4 + (quad ^ ((ra >> 1) & 3))) * 8;
    }
    #pragma unroll
    for (int j = 0; j < 4; ++j) {
        int rb = brow0 + j * 16 + l15;
        boff[j] = (rb * 4 + (quad ^ ((rb >> 1) & 3))) * 8;
    }

    f32x4 acc[2][4];
    #pragma unroll
    for (int i = 0; i < 2; ++i)
        #pragma unroll
        for (int j = 0; j < 4; ++j) acc[i][j] = (f32x4){0.f, 0.f, 0.f, 0.f};

    auto stage = [&](int i) {
        int b = i % 3, k0 = i * 32;
        gl_lds16(A + goffA + k0, &As[b][(w * 64) * 8]);
        gl_lds16(W + goffB[0] + k0, &Bs[b][(w * 128 + 0) * 8]);
        gl_lds16(W + goffB[1] + k0, &Bs[b][(w * 128 + 64) * 8]);
    };

    int nk = K >> 5;
    stage(0);
    if (nk > 1) stage(1);
    for (int i = 0; i < nk; ++i) {
        MEMFENCE();
        if (i + 1 < nk) __builtin_amdgcn_s_waitcnt(WAIT_VM3);
        else            __builtin_amdgcn_s_waitcnt(WAIT_VM0);
        __builtin_amdgcn_s_barrier();
        MEMFENCE();
        if (i + 2 < nk) stage(i + 2);

        const unsigned short* Ab = &As[i % 3][0];
        const unsigned short* Bb = &Bs[i % 3][0];
        bf16x8 af[2], bf_[4];
        #pragma unroll
        for (int t = 0; t < 2; ++t) af[t]  = *(const bf16x8*)(Ab + aoff[t]);
        #pragma unroll
        for (int j = 0; j < 4; ++j) bf_[j] = *(const bf16x8*)(Bb + boff[j]);
        #pragma unroll
        for (int i2 = 0; i2 < 2; ++i2)
            #pragma unroll
            for (int j = 0; j < 4; ++j)
                acc[i2][j] = __builtin_amdgcn_mfma_f32_16x16x32_bf16(af[i2], bf_[j], acc[i2][j], 0, 0, 0);
        MEMFENCE();
    }

    #pragma unroll
    for (int i = 0; i < 2; ++i) {
        int row0 = mt0 * 64 + arow0 + i * 16 + quad * 4;
        #pragma unroll
        for (int j = 0; j < 4; ++j) {
            int col = nt0 * 128 + brow0 + j * 16 + l15;
            if (Cf) {
                #pragma unroll
                for (int reg = 0; reg < 4; ++reg)
                    Cf[(size_t)(row0 + reg) * N + col] = acc[i][j][reg];
            } else {
                #pragma unroll
                for (int reg = 0; reg < 4; ++reg)
                    Cb[(size_t)(row0 + reg) * N + col] = f2b(acc[i][j][reg]);
            }
        }
    }
}

// ---------------------------------------------------------------------------
// QKV projection, tile 64x128 (grid 768 = 3 blocks/CU via launch_bounds
// (256,3); was 384 at 1.5/CU).  Triple-buffered K-loop as gemm128.  FUSED
// epilogues: nt0 0..7 = Q (rope+prescale), 8..9 = K (rope), 10..11 = V
// (transpose).  Rope pair (d,d+64) via one Ex exchange round (64-row tile).
// Staging pool (36 KB) aliased with Ex/T epilogue LDS.
// ---------------------------------------------------------------------------
#define QKVW (HIDDEN + 2 * NKV * HD)   // 1536
__global__ __launch_bounds__(256, 3) void gemmqkv(
    const unsigned short* __restrict__ A, const unsigned short* __restrict__ W,
    const int* __restrict__ pos,
    unsigned short* __restrict__ Qb, unsigned short* __restrict__ Kb,
    unsigned short* __restrict__ Vt)
{
    __shared__ alignas(16) char pool[36864];   // 36 KB
    unsigned short (*As)[64 * 32]  = (unsigned short (*)[64 * 32])(pool);           // 3 x 4 KB
    unsigned short (*Bs)[128 * 32] = (unsigned short (*)[128 * 32])(pool + 12288);  // 3 x 8 KB
    float (*Ex)[32][68] = (float (*)[32][68])(pool);     // 34.8 KB (epilogue alias)
    unsigned short* T = (unsigned short*)(pool);         // 16.6 KB (epilogue alias)

    int lane = threadIdx.x & 63;
    int w = threadIdx.x >> 6;
    int l15 = lane & 15, quad = lane >> 4;

    const int K = HIDDEN;
    int mt0 = (int)blockIdx.x / 12;
    int nt0 = (int)blockIdx.x - mt0 * 12;

    size_t goffA;
    {
        int s = w * 64 + lane;
        int row = s >> 2, spos = s & 3;
        int kblk = spos ^ ((row >> 1) & 3);
        goffA = (size_t)(mt0 * 64 + row) * K + kblk * 8;
    }
    size_t goffB[2];
    #pragma unroll
    for (int is = 0; is < 2; ++is) {
        int s = w * 128 + is * 64 + lane;
        int row = s >> 2, spos = s & 3;
        int kblk = spos ^ ((row >> 1) & 3);
        goffB[is] = (size_t)(nt0 * 128 + row) * K + kblk * 8;
    }

    int arow0 = (w >> 1) * 32;
    int brow0 = (w & 1) * 64;
    int aoff[2], boff[4];
    #pragma unroll
    for (int t = 0; t < 2; ++t) {
        int ra = arow0 + t * 16 + l15;
        aoff[t] = (ra * 4 + (quad ^ ((ra >> 1) & 3))) * 8;
    }
    #pragma unroll
    for (int j = 0; j < 4; ++j) {
        int rb = brow0 + j * 16 + l15;
        boff[j] = (rb * 4 + (quad ^ ((rb >> 1) & 3))) * 8;
    }

    f32x4 acc[2][4];
    #pragma unroll
    for (int i = 0; i < 2; ++i)
        #pragma unroll
        for (int j = 0; j < 4; ++j) acc[i][j] = (f32x4){0.f, 0.f, 0.f, 0.f};

    auto stage = [&](int i) {
        int b = i % 3, k0 = i * 32;
        gl_lds16(A + goffA + k0, &As[b][(w * 64) * 8]);
        gl_lds16(W + goffB[0] + k0, &Bs[b][(w * 128 + 0) * 8]);
        gl_lds16(W + goffB[1] + k0, &Bs[b][(w * 128 + 64) * 8]);
    };

    stage(0);
    stage(1);
    for (int i = 0; i < 32; ++i) {
        MEMFENCE();
        if (i + 1 < 32) __builtin_amdgcn_s_waitcnt(WAIT_VM3);
        else            __builtin_amdgcn_s_waitcnt(WAIT_VM0);
        __builtin_amdgcn_s_barrier();
        MEMFENCE();
        if (i + 2 < 32) stage(i + 2);

        const unsigned short* Ab = &As[i % 3][0];
        const unsigned short* Bb = &Bs[i % 3][0];
        bf16x8 af[2], bf_[4];
        #pragma unroll
        for (int t = 0; t < 2; ++t) af[t]  = *(const bf16x8*)(Ab + aoff[t]);
        #pragma unroll
        for (int j = 0; j < 4; ++j) bf_[j] = *(const bf16x8*)(Bb + boff[j]);
        #pragma unroll
        for (int i2 = 0; i2 < 2; ++i2)
            #pragma unroll
            for (int j = 0; j < 4; ++j)
                acc[i2][j] = __builtin_amdgcn_mfma_f32_16x16x32_bf16(af[i2], bf_[j], acc[i2][j], 0, 0, 0);
        MEMFENCE();
    }

    if (nt0 >= 10) {
        // ---- V: bf16 -> LDS tile [64 s][130 d-stride] -> transposed Vt
        int kv = nt0 - 10;
        __syncthreads();   // all K-loop LDS reads done before pool reuse
        #pragma unroll
        for (int i = 0; i < 2; ++i) {
            int srow = arow0 + i * 16 + quad * 4;
            #pragma unroll
            for (int j = 0; j < 4; ++j) {
                int d = brow0 + j * 16 + l15;
                #pragma unroll
                for (int reg = 0; reg < 4; ++reg)
                    T[(srow + reg) * 130 + d] = f2b(acc[i][j][reg]);
            }
        }
        __syncthreads();
        int tid = threadIdx.x;
        int dl = tid >> 4;               // 0..15
        int s4 = (tid & 15) * 4;         // s chunk (0..60)
        #pragma unroll
        for (int it = 0; it < 8; ++it) {
            int d = it * 16 + dl;
            u16x4 v4 = { T[(s4 + 0) * 130 + d], T[(s4 + 1) * 130 + d],
                         T[(s4 + 2) * 130 + d], T[(s4 + 3) * 130 + d] };
            *(u16x4*)(Vt + (size_t)kv * HD * S_LEN + (size_t)d * S_LEN
                      + mt0 * 64 + s4) = v4;
        }
        return;
    }

    // ---- Q/K: rope epilogue (one exchange round; 32 rows per wave-pair)
    bool isQ = (nt0 < 8);
    int kv = nt0 - 8;
    bool is64 = (pos[1] == 0) && (pos[3] == 0);
    const float qscale = 0.08838834764831843f;

    float invf[4];
    #pragma unroll
    for (int j = 0; j < 4; ++j) {
        int d6 = (brow0 + j * 16 + l15) & 63;
        invf[j] = exp2f(-(float)d6 * (13.287712379549449f / 64.0f));
    }

    __syncthreads();   // K-loop LDS reads done before pool reuse
    #pragma unroll
    for (int i = 0; i < 2; ++i)
        #pragma unroll
        for (int j = 0; j < 4; ++j)
            #pragma unroll
            for (int reg = 0; reg < 4; ++reg)
                Ex[w][i * 16 + quad * 4 + reg][j * 16 + l15] = acc[i][j][reg];
    __syncthreads();
    #pragma unroll
    for (int i = 0; i < 2; ++i) {
        #pragma unroll
        for (int reg = 0; reg < 4; ++reg) {
            int s = mt0 * 64 + arow0 + i * 16 + quad * 4 + reg;
            int pv_ = is64 ? pos[2 * s] : pos[s];
            float pf = (float)pv_;
            #pragma unroll
            for (int j = 0; j < 4; ++j) {
                float sn, cs;
                __sincosf(pf * invf[j], &sn, &cs);
                float a  = acc[i][j][reg];
                float pr = Ex[w ^ 1][i * 16 + quad * 4 + reg][j * 16 + l15];
                int d_local = brow0 + j * 16 + l15;
                float outv = (d_local < 64) ? (a * cs - pr * sn) : (a * cs + pr * sn);
                if (isQ) {
                    Qb[(size_t)s * HIDDEN + nt0 * HD + d_local] = f2b(outv * qscale);
                } else {
                    Kb[(size_t)kv * S_LEN * HD + (size_t)s * HD + d_local] = f2b(outv);
                }
            }
        }
    }
}

// ---------------------------------------------------------------------------
// Flash attention — R15 config restored (best measured: 64.2 us), with the
// R16 window-base fix.  64-key chunks, 16 q/wave, 512 blocks = 2 blocks/CU,
// register-direct P (S^T operand swap), single barrier/chunk, mirrored
// q-tile swizzle.  R16 (32 q/wave) proved the grid collapses to 1 wave/SIMD
// and fully exposes latency: do not reduce wave count below 2/SIMD.
// ---------------------------------------------------------------------------
__global__ __launch_bounds__(256, 2) void attn_coop(
    const unsigned short* __restrict__ Qb, const unsigned short* __restrict__ Kb,
    const unsigned short* __restrict__ Vt, unsigned short* __restrict__ Ctx)
{
    __shared__ alignas(16) unsigned short Klds[2][64 * 128];   // 32 KB
    __shared__ alignas(16) unsigned short Vlds[2][128 * 64];   // 32 KB

    int lane = threadIdx.x & 63;
    int w = threadIdx.x >> 6;
    int l15 = lane & 15, quad = lane >> 4;
    int h = blockIdx.y;
    int kv = h >> 2;                 // GROUPS = 4
    int qt = (h & 4) ? (63 - (int)blockIdx.x) : (int)blockIdx.x;
    int qb = qt * 64;
    int q16 = qb + w * 16;

    bf16x8 a_q[4];
    const unsigned short* qrow = Qb + (size_t)(q16 + l15) * HIDDEN + h * HD + quad * 8;
    #pragma unroll
    for (int st = 0; st < 4; ++st) a_q[st] = *(const bf16x8*)(qrow + st * 32);

    bf16x4 ones4;
    #pragma unroll
    for (int i = 0; i < 4; ++i) ones4[i] = (short)0x3F80;   // bf16 1.0

    int lo = qb - (WIN - 1); if (lo < 0) lo = 0; lo &= ~63;
    int nch = (qb + 64 - lo) >> 6;   // <= 33

    const unsigned short* gbase;
    unsigned short* ldsdst[2];
    int myoff[8];
    int jmul;
    if (w < 2) {
        gbase = Kb + (size_t)kv * S_LEN * HD;
        ldsdst[0] = &Klds[0][w * 8 * 512];
        ldsdst[1] = &Klds[1][w * 8 * 512];
        jmul = HD;
        #pragma unroll
        for (int tt = 0; tt < 8; ++tt) {
            int t = w * 8 + tt;
            int key  = t * 4 + (lane >> 4);
            int dblk = (lane & 15) ^ (key & 15);
            myoff[tt] = key * HD + dblk * 8;
        }
    } else {
        gbase = Vt + (size_t)kv * HD * S_LEN;
        ldsdst[0] = &Vlds[0][(w - 2) * 8 * 512];
        ldsdst[1] = &Vlds[1][(w - 2) * 8 * 512];
        jmul = 1;
        #pragma unroll
        for (int tt = 0; tt < 8; ++tt) {
            int t = (w - 2) * 8 + tt;
            int d    = t * 8 + (lane >> 3);
            int kblk = (lane & 7) ^ (d & 7);
            myoff[tt] = d * S_LEN + kblk * 8;
        }
    }

    auto issue = [&](int c) {
        int j0 = lo + c * 64;
        const unsigned short* src = gbase + (size_t)j0 * jmul;
        unsigned short* dst = ldsdst[c & 1];
        #pragma unroll
        for (int tt = 0; tt < 8; ++tt)
            gl_lds16(src + myoff[tt], dst + tt * 512);
    };

    f32x4 o[9];                      // o[0..7] = d-tiles, o[8] = row-sums l
    #pragma unroll
    for (int nd = 0; nd < 9; ++nd) o[nd] = (f32x4){0.f, 0.f, 0.f, 0.f};

    issue(0);

    for (int c = 0; c < nch; ++c) {
        int j0 = lo + c * 64;

        MEMFENCE();
        __builtin_amdgcn_s_waitcnt(WAIT_VM0);   // my slice of chunk c landed
        __builtin_amdgcn_s_barrier();           // chunk staged; buf[c-1] drained
        MEMFENCE();
        if (c + 1 < nch) issue(c + 1);

        const unsigned short* Kc = &Klds[c & 1][0];
        const unsigned short* Vc = &Vlds[c & 1][0];

        // ---- S^T tiles: [16 keys x 16 queries], A = K-frag, B = Q-frag
        f32x4 sc[4];
        #pragma unroll
        for (int t = 0; t < 4; ++t) {
            sc[t] = (f32x4){0.f, 0.f, 0.f, 0.f};
            int key = t * 16 + l15;
            #pragma unroll
            for (int st = 0; st < 4; ++st) {
                int off16 = key * 16 + ((st * 4 + quad) ^ (key & 15));
                bf16x8 ak = *(const bf16x8*)(Kc + off16 * 8);
                sc[t] = __builtin_amdgcn_mfma_f32_16x16x32_bf16(ak, a_q[st], sc[t], 0, 0, 0);
            }
        }

        // ---- P^T = exp(S^T): row = key (quad*4+reg), col = query (l15)
        float p[4][4];
        if (j0 + 63 <= q16 && j0 > q16 + 15 - WIN) {
            #pragma unroll
            for (int t = 0; t < 4; ++t)
                #pragma unroll
                for (int reg = 0; reg < 4; ++reg) p[t][reg] = __expf(sc[t][reg]);
        } else {
            int iq = q16 + l15;
            #pragma unroll
            for (int t = 0; t < 4; ++t) {
                #pragma unroll
                for (int reg = 0; reg < 4; ++reg) {
                    int key = j0 + t * 16 + quad * 4 + reg;
                    p[t][reg] = (key <= iq && key > iq - WIN) ? __expf(sc[t][reg]) : 0.f;
                }
            }
        }

        // ---- pack P into K=16 A-fragments — no LDS round-trip
        bf16x4 a_p[4];
        #pragma unroll
        for (int t = 0; t < 4; ++t) {
            a_p[t][0] = (short)f2b(p[t][0]);
            a_p[t][1] = (short)f2b(p[t][1]);
            a_p[t][2] = (short)f2b(p[t][2]);
            a_p[t][3] = (short)f2b(p[t][3]);
        }

        // ---- O += P@V, l += P@1 : 4 key-groups x (8 d-tiles + 1), K=16
        #pragma unroll
        for (int t = 0; t < 4; ++t) {
            #pragma unroll
            for (int nd = 0; nd < 8; ++nd) {
                int d = nd * 16 + l15;
                int kblk = t * 2 + (quad >> 1);
                int slot = d * 8 + (kblk ^ (d & 7));
                bf16x4 bv = *(const bf16x4*)(Vc + slot * 8 + (quad & 1) * 4);
                o[nd] = __builtin_amdgcn_mfma_f32_16x16x16bf16_1k(a_p[t], bv, o[nd], 0, 0, 0);
            }
            o[8] = __builtin_amdgcn_mfma_f32_16x16x16bf16_1k(a_p[t], ones4, o[8], 0, 0, 0);
        }
        MEMFENCE();
    }

    // ---- epilogue: ctx = O / l (O C-layout: col=l15=d, row=quad*4+reg=q)
    #pragma unroll
    for (int nd = 0; nd < 8; ++nd) {
        int d = nd * 16 + l15;
        #pragma unroll
        for (int reg = 0; reg < 4; ++reg) {
            int q = q16 + quad * 4 + reg;
            Ctx[(size_t)q * HIDDEN + h * HD + d] = f2b(o[nd][reg] / o[8][reg]);
        }
    }
}

// ---------------------------------------------------------------------------
extern "C" void kernel_launch(void* const* d_in, const int* in_sizes, int n_in,
                              void* d_out, int out_size, void* d_ws, size_t ws_size,
                              hipStream_t stream)
{
    const float* hidden = (const float*)d_in[0];
    const float* wq = (const float*)d_in[1];
    const float* wk = (const float*)d_in[2];
    const float* wv = (const float*)d_in[3];
    const float* wo = (const float*)d_in[4];
    const int* pos = (const int*)d_in[5];
    float* out = (float*)d_out;

    char* ws = (char*)d_ws;
    size_t off = 0;
    unsigned short* Hb   = (unsigned short*)(ws + off); off += (size_t)S_LEN * HIDDEN * 2;
    unsigned short* Wqkv = (unsigned short*)(ws + off); off += (size_t)QKVW * HIDDEN * 2;
    unsigned short* Wob  = (unsigned short*)(ws + off); off += (size_t)HIDDEN * HIDDEN * 2;
    unsigned short* Qb   = (unsigned short*)(ws + off); off += (size_t)S_LEN * HIDDEN * 2;
    unsigned short* Kb   = (unsigned short*)(ws + off); off += (size_t)S_LEN * NKV * HD * 2;
    unsigned short* Vt   = (unsigned short*)(ws + off); off += (size_t)S_LEN * NKV * HD * 2;
    unsigned short* Cb   = (unsigned short*)(ws + off); off += (size_t)S_LEN * HIDDEN * 2;

    const int n_h  = S_LEN * HIDDEN / 4;
    const int n_wq = HIDDEN * HIDDEN / 4;
    const int n_wk = NKV * HD * HIDDEN / 4;
    int tot4 = n_h + n_wq + 2 * n_wk + n_wq;
    cvt5<<<(tot4 + 255) / 256, 256, 0, stream>>>(
        hidden, Hb, n_h,
        wq, Wqkv, n_wq,
        wk, Wqkv + (size_t)HIDDEN * HIDDEN, n_wk,
        wv, Wqkv + (size_t)(HIDDEN + NKV * HD) * HIDDEN, n_wk,
        wo, Wob, n_wq);

    // fused QKV projection + RoPE + V-transpose, 64x128 tiles (768 blocks)
    gemmqkv<<<(S_LEN / 64) * 12, 256, 0, stream>>>(
        Hb, Wqkv, pos, Qb, Kb, Vt);

    // flash attention (R15 config, 512 blocks)
    attn_coop<<<dim3(S_LEN / 64, NH), 256, 0, stream>>>(Qb, Kb, Vt, Cb);

    // output projection -> fp32 d_out, 64x128 tiles (512 blocks)
    gemm128<<<(S_LEN / 64) * (HIDDEN / 128), 256, 0, stream>>>(
        Cb, Wob, out, nullptr, S_LEN, HIDDEN, HIDDEN);
}

// Round 18
// 185.980 us; speedup vs baseline: 1.0862x; 1.0066x over previous
//
#include <hip/hip_runtime.h>

#define S_LEN 4096
#define HIDDEN 1024
#define NH 8
#define NKV 2
#define HD 128
#define WIN 2048

typedef short bf16x8 __attribute__((ext_vector_type(8)));
typedef short bf16x4 __attribute__((ext_vector_type(4)));
typedef float f32x4 __attribute__((ext_vector_type(4)));
typedef unsigned short u16x4 __attribute__((ext_vector_type(4)));

__device__ __forceinline__ unsigned short f2b(float f) {
    unsigned int u = __builtin_bit_cast(unsigned int, f);
    u += 0x7fffu + ((u >> 16) & 1u);     // round-to-nearest-even
    return (unsigned short)(u >> 16);
}
__device__ __forceinline__ float b2f(unsigned short u) {
    unsigned int x = ((unsigned int)u) << 16;
    return __builtin_bit_cast(float, x);
}

// async global->LDS, 16B per lane, lands at ldsbase + lane*16 (wave-uniform base)
__device__ __forceinline__ void gl_lds16(const unsigned short* g, unsigned short* l) {
    __builtin_amdgcn_global_load_lds(
        (const __attribute__((address_space(1))) unsigned int*)g,
        (__attribute__((address_space(3))) unsigned int*)l, 16, 0, 0);
}

// s_waitcnt immediates (gfx9): vmcnt[3:0]|[15:14], exp[6:4], lgkm[11:8]
#define WAIT_VM6   0x0F76   // vmcnt<=6
#define WAIT_VM0   0x0F70   // vmcnt==0
#define MEMFENCE() __asm__ volatile("" ::: "memory")

// ---------------------------------------------------------------------------
// One-shot fp32 -> bf16 of the five input tensors (float4 granularity).
// ---------------------------------------------------------------------------
__global__ __launch_bounds__(256) void cvt5(
    const float* __restrict__ s0, unsigned short* __restrict__ t0, int n0,
    const float* __restrict__ s1, unsigned short* __restrict__ t1, int n1,
    const float* __restrict__ s2, unsigned short* __restrict__ t2, int n2,
    const float* __restrict__ s3, unsigned short* __restrict__ t3, int n3,
    const float* __restrict__ s4, unsigned short* __restrict__ t4, int n4)
{
    int i = blockIdx.x * 256 + threadIdx.x;   // float4 index
    const float* s; unsigned short* t;
    if (i < n0)              { s = s0; t = t0; }
    else if ((i -= n0) < n1) { s = s1; t = t1; }
    else if ((i -= n1) < n2) { s = s2; t = t2; }
    else if ((i -= n2) < n3) { s = s3; t = t3; }
    else if ((i -= n3) < n4) { s = s4; t = t4; }
    else return;
    f32x4 v = *(const f32x4*)(s + (size_t)i * 4);
    u16x4 r = { f2b(v[0]), f2b(v[1]), f2b(v[2]), f2b(v[3]) };
    *(u16x4*)(t + (size_t)i * 4) = r;
}

// ---------------------------------------------------------------------------
// Output projection GEMM, tile 64x128, QUAD-buffered K-loop (R18): prologue
// stages tiles 0..2; iter i waits vmcnt(6) (tile i landed, i+1/i+2 in
// flight), barrier, stages i+3 -> THREE iterations of L2-latency cover.
// R15/R17 showed occupancy changes are neutral: the bound is uncovered
// per-iteration latency (all waves share the same vmcnt wait).
// ---------------------------------------------------------------------------
__global__ __launch_bounds__(256, 2) void gemm128(
    const unsigned short* __restrict__ A, const unsigned short* __restrict__ W,
    float* __restrict__ Cf, unsigned short* __restrict__ Cb,
    int M, int N, int K)
{
    __shared__ alignas(16) unsigned short As[4][64 * 32];    // 16 KB
    __shared__ alignas(16) unsigned short Bs[4][128 * 32];   // 32 KB

    int lane = threadIdx.x & 63;
    int w = threadIdx.x >> 6;
    int l15 = lane & 15, quad = lane >> 4;

    int tiles_n = N >> 7;
    int mt0 = (int)blockIdx.x / tiles_n;
    int nt0 = (int)blockIdx.x - mt0 * tiles_n;

    size_t goffA;
    {
        int s = w * 64 + lane;
        int row = s >> 2, spos = s & 3;
        int kblk = spos ^ ((row >> 1) & 3);
        goffA = (size_t)(mt0 * 64 + row) * K + kblk * 8;
    }
    size_t goffB[2];
    #pragma unroll
    for (int is = 0; is < 2; ++is) {
        int s = w * 128 + is * 64 + lane;
        int row = s >> 2, spos = s & 3;
        int kblk = spos ^ ((row >> 1) & 3);
        goffB[is] = (size_t)(nt0 * 128 + row) * K + kblk * 8;
    }

    int arow0 = (w >> 1) * 32;
    int brow0 = (w & 1) * 64;
    int aoff[2], boff[4];
    #pragma unroll
    for (int t = 0; t < 2; ++t) {
        int ra = arow0 + t * 16 + l15;
        aoff[t] = (ra * 4 + (quad ^ ((ra >> 1) & 3))) * 8;
    }
    #pragma unroll
    for (int j = 0; j < 4; ++j) {
        int rb = brow0 + j * 16 + l15;
        boff[j] = (rb * 4 + (quad ^ ((rb >> 1) & 3))) * 8;
    }

    f32x4 acc[2][4];
    #pragma unroll
    for (int i = 0; i < 2; ++i)
        #pragma unroll
        for (int j = 0; j < 4; ++j) acc[i][j] = (f32x4){0.f, 0.f, 0.f, 0.f};

    auto stage = [&](int i) {
        int b = i & 3, k0 = i * 32;
        gl_lds16(A + goffA + k0, &As[b][(w * 64) * 8]);
        gl_lds16(W + goffB[0] + k0, &Bs[b][(w * 128 + 0) * 8]);
        gl_lds16(W + goffB[1] + k0, &Bs[b][(w * 128 + 64) * 8]);
    };

    int nk = K >> 5;
    stage(0);
    if (nk > 1) stage(1);
    if (nk > 2) stage(2);
    for (int i = 0; i < nk; ++i) {
        MEMFENCE();
        if (i + 1 < nk) __builtin_amdgcn_s_waitcnt(WAIT_VM6);
        else            __builtin_amdgcn_s_waitcnt(WAIT_VM0);
        __builtin_amdgcn_s_barrier();
        MEMFENCE();
        if (i + 3 < nk) stage(i + 3);

        const unsigned short* Ab = &As[i & 3][0];
        const unsigned short* Bb = &Bs[i & 3][0];
        bf16x8 af[2], bf_[4];
        #pragma unroll
        for (int t = 0; t < 2; ++t) af[t]  = *(const bf16x8*)(Ab + aoff[t]);
        #pragma unroll
        for (int j = 0; j < 4; ++j) bf_[j] = *(const bf16x8*)(Bb + boff[j]);
        #pragma unroll
        for (int i2 = 0; i2 < 2; ++i2)
            #pragma unroll
            for (int j = 0; j < 4; ++j)
                acc[i2][j] = __builtin_amdgcn_mfma_f32_16x16x32_bf16(af[i2], bf_[j], acc[i2][j], 0, 0, 0);
        MEMFENCE();
    }

    #pragma unroll
    for (int i = 0; i < 2; ++i) {
        int row0 = mt0 * 64 + arow0 + i * 16 + quad * 4;
        #pragma unroll
        for (int j = 0; j < 4; ++j) {
            int col = nt0 * 128 + brow0 + j * 16 + l15;
            if (Cf) {
                #pragma unroll
                for (int reg = 0; reg < 4; ++reg)
                    Cf[(size_t)(row0 + reg) * N + col] = acc[i][j][reg];
            } else {
                #pragma unroll
                for (int reg = 0; reg < 4; ++reg)
                    Cb[(size_t)(row0 + reg) * N + col] = f2b(acc[i][j][reg]);
            }
        }
    }
}

// ---------------------------------------------------------------------------
// QKV projection, tile 64x128, QUAD-buffered K-loop (see gemm128 note).
// FUSED epilogues: nt0 0..7 = Q (rope+prescale), 8..9 = K (rope), 10..11 =
// V (transpose).  Staging pool (48 KB) aliased with Ex/T epilogue LDS.
// ---------------------------------------------------------------------------
#define QKVW (HIDDEN + 2 * NKV * HD)   // 1536
__global__ __launch_bounds__(256, 3) void gemmqkv(
    const unsigned short* __restrict__ A, const unsigned short* __restrict__ W,
    const int* __restrict__ pos,
    unsigned short* __restrict__ Qb, unsigned short* __restrict__ Kb,
    unsigned short* __restrict__ Vt)
{
    __shared__ alignas(16) char pool[49152];   // 48 KB
    unsigned short (*As)[64 * 32]  = (unsigned short (*)[64 * 32])(pool);           // 4 x 4 KB
    unsigned short (*Bs)[128 * 32] = (unsigned short (*)[128 * 32])(pool + 16384);  // 4 x 8 KB
    float (*Ex)[32][68] = (float (*)[32][68])(pool);     // 34.8 KB (epilogue alias)
    unsigned short* T = (unsigned short*)(pool);         // 16.6 KB (epilogue alias)

    int lane = threadIdx.x & 63;
    int w = threadIdx.x >> 6;
    int l15 = lane & 15, quad = lane >> 4;

    const int K = HIDDEN;
    int mt0 = (int)blockIdx.x / 12;
    int nt0 = (int)blockIdx.x - mt0 * 12;

    size_t goffA;
    {
        int s = w * 64 + lane;
        int row = s >> 2, spos = s & 3;
        int kblk = spos ^ ((row >> 1) & 3);
        goffA = (size_t)(mt0 * 64 + row) * K + kblk * 8;
    }
    size_t goffB[2];
    #pragma unroll
    for (int is = 0; is < 2; ++is) {
        int s = w * 128 + is * 64 + lane;
        int row = s >> 2, spos = s & 3;
        int kblk = spos ^ ((row >> 1) & 3);
        goffB[is] = (size_t)(nt0 * 128 + row) * K + kblk * 8;
    }

    int arow0 = (w >> 1) * 32;
    int brow0 = (w & 1) * 64;
    int aoff[2], boff[4];
    #pragma unroll
    for (int t = 0; t < 2; ++t) {
        int ra = arow0 + t * 16 + l15;
        aoff[t] = (ra * 4 + (quad ^ ((ra >> 1) & 3))) * 8;
    }
    #pragma unroll
    for (int j = 0; j < 4; ++j) {
        int rb = brow0 + j * 16 + l15;
        boff[j] = (rb * 4 + (quad ^ ((rb >> 1) & 3))) * 8;
    }

    f32x4 acc[2][4];
    #pragma unroll
    for (int i = 0; i < 2; ++i)
        #pragma unroll
        for (int j = 0; j < 4; ++j) acc[i][j] = (f32x4){0.f, 0.f, 0.f, 0.f};

    auto stage = [&](int i) {
        int b = i & 3, k0 = i * 32;
        gl_lds16(A + goffA + k0, &As[b][(w * 64) * 8]);
        gl_lds16(W + goffB[0] + k0, &Bs[b][(w * 128 + 0) * 8]);
        gl_lds16(W + goffB[1] + k0, &Bs[b][(w * 128 + 64) * 8]);
    };

    stage(0);
    stage(1);
    stage(2);
    for (int i = 0; i < 32; ++i) {
        MEMFENCE();
        if (i + 1 < 32) __builtin_amdgcn_s_waitcnt(WAIT_VM6);
        else            __builtin_amdgcn_s_waitcnt(WAIT_VM0);
        __builtin_amdgcn_s_barrier();
        MEMFENCE();
        if (i + 3 < 32) stage(i + 3);

        const unsigned short* Ab = &As[i & 3][0];
        const unsigned short* Bb = &Bs[i & 3][0];
        bf16x8 af[2], bf_[4];
        #pragma unroll
        for (int t = 0; t < 2; ++t) af[t]  = *(const bf16x8*)(Ab + aoff[t]);
        #pragma unroll
        for (int j = 0; j < 4; ++j) bf_[j] = *(const bf16x8*)(Bb + boff[j]);
        #pragma unroll
        for (int i2 = 0; i2 < 2; ++i2)
            #pragma unroll
            for (int j = 0; j < 4; ++j)
                acc[i2][j] = __builtin_amdgcn_mfma_f32_16x16x32_bf16(af[i2], bf_[j], acc[i2][j], 0, 0, 0);
        MEMFENCE();
    }

    if (nt0 >= 10) {
        // ---- V: bf16 -> LDS tile [64 s][130 d-stride] -> transposed Vt
        int kv = nt0 - 10;
        __syncthreads();   // all K-loop LDS reads done before pool reuse
        #pragma unroll
        for (int i = 0; i < 2; ++i) {
            int srow = arow0 + i * 16 + quad * 4;
            #pragma unroll
            for (int j = 0; j < 4; ++j) {
                int d = brow0 + j * 16 + l15;
                #pragma unroll
                for (int reg = 0; reg < 4; ++reg)
                    T[(srow + reg) * 130 + d] = f2b(acc[i][j][reg]);
            }
        }
        __syncthreads();
        int tid = threadIdx.x;
        int dl = tid >> 4;               // 0..15
        int s4 = (tid & 15) * 4;         // s chunk (0..60)
        #pragma unroll
        for (int it = 0; it < 8; ++it) {
            int d = it * 16 + dl;
            u16x4 v4 = { T[(s4 + 0) * 130 + d], T[(s4 + 1) * 130 + d],
                         T[(s4 + 2) * 130 + d], T[(s4 + 3) * 130 + d] };
            *(u16x4*)(Vt + (size_t)kv * HD * S_LEN + (size_t)d * S_LEN
                      + mt0 * 64 + s4) = v4;
        }
        return;
    }

    // ---- Q/K: rope epilogue (one exchange round)
    bool isQ = (nt0 < 8);
    int kv = nt0 - 8;
    bool is64 = (pos[1] == 0) && (pos[3] == 0);
    const float qscale = 0.08838834764831843f;

    float invf[4];
    #pragma unroll
    for (int j = 0; j < 4; ++j) {
        int d6 = (brow0 + j * 16 + l15) & 63;
        invf[j] = exp2f(-(float)d6 * (13.287712379549449f / 64.0f));
    }

    __syncthreads();   // K-loop LDS reads done before pool reuse
    #pragma unroll
    for (int i = 0; i < 2; ++i)
        #pragma unroll
        for (int j = 0; j < 4; ++j)
            #pragma unroll
            for (int reg = 0; reg < 4; ++reg)
                Ex[w][i * 16 + quad * 4 + reg][j * 16 + l15] = acc[i][j][reg];
    __syncthreads();
    #pragma unroll
    for (int i = 0; i < 2; ++i) {
        #pragma unroll
        for (int reg = 0; reg < 4; ++reg) {
            int s = mt0 * 64 + arow0 + i * 16 + quad * 4 + reg;
            int pv_ = is64 ? pos[2 * s] : pos[s];
            float pf = (float)pv_;
            #pragma unroll
            for (int j = 0; j < 4; ++j) {
                float sn, cs;
                __sincosf(pf * invf[j], &sn, &cs);
                float a  = acc[i][j][reg];
                float pr = Ex[w ^ 1][i * 16 + quad * 4 + reg][j * 16 + l15];
                int d_local = brow0 + j * 16 + l15;
                float outv = (d_local < 64) ? (a * cs - pr * sn) : (a * cs + pr * sn);
                if (isQ) {
                    Qb[(size_t)s * HIDDEN + nt0 * HD + d_local] = f2b(outv * qscale);
                } else {
                    Kb[(size_t)kv * S_LEN * HD + (size_t)s * HD + d_local] = f2b(outv);
                }
            }
        }
    }
}

// ---------------------------------------------------------------------------
// Flash attention — frozen (best: 64.2-65.7 us).  64-key chunks, 16 q/wave,
// 512 blocks = 2 blocks/CU, register-direct P (S^T operand swap), single
// barrier/chunk, mirrored q-tile swizzle, window-base covers first query.
// ---------------------------------------------------------------------------
__global__ __launch_bounds__(256, 2) void attn_coop(
    const unsigned short* __restrict__ Qb, const unsigned short* __restrict__ Kb,
    const unsigned short* __restrict__ Vt, unsigned short* __restrict__ Ctx)
{
    __shared__ alignas(16) unsigned short Klds[2][64 * 128];   // 32 KB
    __shared__ alignas(16) unsigned short Vlds[2][128 * 64];   // 32 KB

    int lane = threadIdx.x & 63;
    int w = threadIdx.x >> 6;
    int l15 = lane & 15, quad = lane >> 4;
    int h = blockIdx.y;
    int kv = h >> 2;                 // GROUPS = 4
    int qt = (h & 4) ? (63 - (int)blockIdx.x) : (int)blockIdx.x;
    int qb = qt * 64;
    int q16 = qb + w * 16;

    bf16x8 a_q[4];
    const unsigned short* qrow = Qb + (size_t)(q16 + l15) * HIDDEN + h * HD + quad * 8;
    #pragma unroll
    for (int st = 0; st < 4; ++st) a_q[st] = *(const bf16x8*)(qrow + st * 32);

    bf16x4 ones4;
    #pragma unroll
    for (int i = 0; i < 4; ++i) ones4[i] = (short)0x3F80;   // bf16 1.0

    int lo = qb - (WIN - 1); if (lo < 0) lo = 0; lo &= ~63;
    int nch = (qb + 64 - lo) >> 6;   // <= 33

    const unsigned short* gbase;
    unsigned short* ldsdst[2];
    int myoff[8];
    int jmul;
    if (w < 2) {
        gbase = Kb + (size_t)kv * S_LEN * HD;
        ldsdst[0] = &Klds[0][w * 8 * 512];
        ldsdst[1] = &Klds[1][w * 8 * 512];
        jmul = HD;
        #pragma unroll
        for (int tt = 0; tt < 8; ++tt) {
            int t = w * 8 + tt;
            int key  = t * 4 + (lane >> 4);
            int dblk = (lane & 15) ^ (key & 15);
            myoff[tt] = key * HD + dblk * 8;
        }
    } else {
        gbase = Vt + (size_t)kv * HD * S_LEN;
        ldsdst[0] = &Vlds[0][(w - 2) * 8 * 512];
        ldsdst[1] = &Vlds[1][(w - 2) * 8 * 512];
        jmul = 1;
        #pragma unroll
        for (int tt = 0; tt < 8; ++tt) {
            int t = (w - 2) * 8 + tt;
            int d    = t * 8 + (lane >> 3);
            int kblk = (lane & 7) ^ (d & 7);
            myoff[tt] = d * S_LEN + kblk * 8;
        }
    }

    auto issue = [&](int c) {
        int j0 = lo + c * 64;
        const unsigned short* src = gbase + (size_t)j0 * jmul;
        unsigned short* dst = ldsdst[c & 1];
        #pragma unroll
        for (int tt = 0; tt < 8; ++tt)
            gl_lds16(src + myoff[tt], dst + tt * 512);
    };

    f32x4 o[9];                      // o[0..7] = d-tiles, o[8] = row-sums l
    #pragma unroll
    for (int nd = 0; nd < 9; ++nd) o[nd] = (f32x4){0.f, 0.f, 0.f, 0.f};

    issue(0);

    for (int c = 0; c < nch; ++c) {
        int j0 = lo + c * 64;

        MEMFENCE();
        __builtin_amdgcn_s_waitcnt(WAIT_VM0);   // my slice of chunk c landed
        __builtin_amdgcn_s_barrier();           // chunk staged; buf[c-1] drained
        MEMFENCE();
        if (c + 1 < nch) issue(c + 1);

        const unsigned short* Kc = &Klds[c & 1][0];
        const unsigned short* Vc = &Vlds[c & 1][0];

        // ---- S^T tiles: [16 keys x 16 queries], A = K-frag, B = Q-frag
        f32x4 sc[4];
        #pragma unroll
        for (int t = 0; t < 4; ++t) {
            sc[t] = (f32x4){0.f, 0.f, 0.f, 0.f};
            int key = t * 16 + l15;
            #pragma unroll
            for (int st = 0; st < 4; ++st) {
                int off16 = key * 16 + ((st * 4 + quad) ^ (key & 15));
                bf16x8 ak = *(const bf16x8*)(Kc + off16 * 8);
                sc[t] = __builtin_amdgcn_mfma_f32_16x16x32_bf16(ak, a_q[st], sc[t], 0, 0, 0);
            }
        }

        // ---- P^T = exp(S^T): row = key (quad*4+reg), col = query (l15)
        float p[4][4];
        if (j0 + 63 <= q16 && j0 > q16 + 15 - WIN) {
            #pragma unroll
            for (int t = 0; t < 4; ++t)
                #pragma unroll
                for (int reg = 0; reg < 4; ++reg) p[t][reg] = __expf(sc[t][reg]);
        } else {
            int iq = q16 + l15;
            #pragma unroll
            for (int t = 0; t < 4; ++t) {
                #pragma unroll
                for (int reg = 0; reg < 4; ++reg) {
                    int key = j0 + t * 16 + quad * 4 + reg;
                    p[t][reg] = (key <= iq && key > iq - WIN) ? __expf(sc[t][reg]) : 0.f;
                }
            }
        }

        // ---- pack P into K=16 A-fragments — no LDS round-trip
        bf16x4 a_p[4];
        #pragma unroll
        for (int t = 0; t < 4; ++t) {
            a_p[t][0] = (short)f2b(p[t][0]);
            a_p[t][1] = (short)f2b(p[t][1]);
            a_p[t][2] = (short)f2b(p[t][2]);
            a_p[t][3] = (short)f2b(p[t][3]);
        }

        // ---- O += P@V, l += P@1 : 4 key-groups x (8 d-tiles + 1), K=16
        #pragma unroll
        for (int t = 0; t < 4; ++t) {
            #pragma unroll
            for (int nd = 0; nd < 8; ++nd) {
                int d = nd * 16 + l15;
                int kblk = t * 2 + (quad >> 1);
                int slot = d * 8 + (kblk ^ (d & 7));
                bf16x4 bv = *(const bf16x4*)(Vc + slot * 8 + (quad & 1) * 4);
                o[nd] = __builtin_amdgcn_mfma_f32_16x16x16bf16_1k(a_p[t], bv, o[nd], 0, 0, 0);
            }
            o[8] = __builtin_amdgcn_mfma_f32_16x16x16bf16_1k(a_p[t], ones4, o[8], 0, 0, 0);
        }
        MEMFENCE();
    }

    // ---- epilogue: ctx = O / l (O C-layout: col=l15=d, row=quad*4+reg=q)
    #pragma unroll
    for (int nd = 0; nd < 8; ++nd) {
        int d = nd * 16 + l15;
        #pragma unroll
        for (int reg = 0; reg < 4; ++reg) {
            int q = q16 + quad * 4 + reg;
            Ctx[(size_t)q * HIDDEN + h * HD + d] = f2b(o[nd][reg] / o[8][reg]);
        }
    }
}

// ---------------------------------------------------------------------------
extern "C" void kernel_launch(void* const* d_in, const int* in_sizes, int n_in,
                              void* d_out, int out_size, void* d_ws, size_t ws_size,
                              hipStream_t stream)
{
    const float* hidden = (const float*)d_in[0];
    const float* wq = (const float*)d_in[1];
    const float* wk = (const float*)d_in[2];
    const float* wv = (const float*)d_in[3];
    const float* wo = (const float*)d_in[4];
    const int* pos = (const int*)d_in[5];
    float* out = (float*)d_out;

    char* ws = (char*)d_ws;
    size_t off = 0;
    unsigned short* Hb   = (unsigned short*)(ws + off); off += (size_t)S_LEN * HIDDEN * 2;
    unsigned short* Wqkv = (unsigned short*)(ws + off); off += (size_t)QKVW * HIDDEN * 2;
    unsigned short* Wob  = (unsigned short*)(ws + off); off += (size_t)HIDDEN * HIDDEN * 2;
    unsigned short* Qb   = (unsigned short*)(ws + off); off += (size_t)S_LEN * HIDDEN * 2;
    unsigned short* Kb   = (unsigned short*)(ws + off); off += (size_t)S_LEN * NKV * HD * 2;
    unsigned short* Vt   = (unsigned short*)(ws + off); off += (size_t)S_LEN * NKV * HD * 2;
    unsigned short* Cb   = (unsigned short*)(ws + off); off += (size_t)S_LEN * HIDDEN * 2;

    const int n_h  = S_LEN * HIDDEN / 4;
    const int n_wq = HIDDEN * HIDDEN / 4;
    const int n_wk = NKV * HD * HIDDEN / 4;
    int tot4 = n_h + n_wq + 2 * n_wk + n_wq;
    cvt5<<<(tot4 + 255) / 256, 256, 0, stream>>>(
        hidden, Hb, n_h,
        wq, Wqkv, n_wq,
        wk, Wqkv + (size_t)HIDDEN * HIDDEN, n_wk,
        wv, Wqkv + (size_t)(HIDDEN + NKV * HD) * HIDDEN, n_wk,
        wo, Wob, n_wq);

    // fused QKV projection + RoPE + V-transpose, 64x128 tiles (768 blocks)
    gemmqkv<<<(S_LEN / 64) * 12, 256, 0, stream>>>(
        Hb, Wqkv, pos, Qb, Kb, Vt);

    // flash attention (frozen config, 512 blocks)
    attn_coop<<<dim3(S_LEN / 64, NH), 256, 0, stream>>>(Qb, Kb, Vt, Cb);

    // output projection -> fp32 d_out, 64x128 tiles (512 blocks)
    gemm128<<<(S_LEN / 64) * (HIDDEN / 128), 256, 0, stream>>>(
        Cb, Wob, out, nullptr, S_LEN, HIDDEN, HIDDEN);
}